// Round 6
// baseline (215.067 us; speedup 1.0000x reference)
//
#include <hip/hip_runtime.h>

// Problem constants (reference: B=64, T=512, D=1024, U=128)
#define TT 512
#define DD 1024
#define UU 128
#define MM 32768            // B*T rows
#define BK 64
#define NCHUNK 16
#define NBUF 3              // circular LDS buffers, prefetch distance 2

typedef short short8 __attribute__((ext_vector_type(8)));   // 8 bf16 (MFMA A/B frag)
typedef float f32x4 __attribute__((ext_vector_type(4)));    // MFMA C/D frag

// fp32 -> bf16 round-to-nearest-even
__device__ __forceinline__ unsigned short f2bf(float f) {
    union { float f; unsigned u; } v; v.f = f;
    unsigned u = v.u;
    return (unsigned short)((u + 0x7fffu + ((u >> 16) & 1u)) >> 16);
}

// async global -> LDS DMA, 16 B/lane. LDS dst = wave-uniform base + lane*16.
__device__ __forceinline__ void glds16(const void* g, void* l) {
    __builtin_amdgcn_global_load_lds(
        (const __attribute__((address_space(1))) void*)g,
        (__attribute__((address_space(3))) void*)l, 16, 0, 0);
}

// ---------------------------------------------------------------------------
// Kernel 0: W[k][n] fp32 (1024x128) -> ws bf16, transposed+chunked:
// wt[kc*8192 + n*64 + k'] = bf16(W[kc*64+k'][n]).   (verified R1-R5)
// ---------------------------------------------------------------------------
__global__ __launch_bounds__(256) void wprep_kernel(const float* __restrict__ w,
                                                    unsigned short* __restrict__ wt) {
    int tg = blockIdx.x * 256 + threadIdx.x;   // 0..16383
    int kg = tg & 7;
    int n  = (tg >> 3) & 127;
    int kc = tg >> 10;
    union { unsigned short s[8]; uint4 v; } o;
#pragma unroll
    for (int j = 0; j < 8; ++j) {
        int k = kc * 64 + kg * 8 + j;
        o.s[j] = f2bf(w[k * 128 + n]);
    }
    *(uint4*)(wt + tg * 8) = o.v;
}

// ---------------------------------------------------------------------------
// Kernel 1: 32(M) x 128(N) per block, 4 waves, each wave 16x64 (4 accs).
// 3-deep circular glds pipeline, prefetch distance 2, manual
// s_waitcnt vmcnt(6)+s_barrier (chunk k+1 loads stay in flight across the
// barrier -- the AITER pattern __syncthreads cannot express).
// LDS: 3 x (A 8KB fp32 + B 16KB bf16) = 72 KB -> 2 blocks/CU.
//
// LDS A: 32 rows x 16 groups(16B).  slot(m,g') holds global group g'^(m&15).
// LDS B: 128 rows x 8 groups(16B).  slot(n,g') holds global group g'^(n&7).
// ---------------------------------------------------------------------------
__global__ __launch_bounds__(256, 2) void crf_energy_kernel(
    const float* __restrict__ x,               // [32768, 1024]
    const int* __restrict__ mask,              // [32768]
    const unsigned short* __restrict__ wt,     // ws: bf16 Wt chunks [16][128][64]
    const float* __restrict__ bias,            // [128]
    const float* __restrict__ lb,              // [128]
    const float* __restrict__ rb,              // [128]
    float* __restrict__ out)                   // [32768, 128]
{
    __shared__ float lAf[NBUF][32 * 64];           // 3 x 8 KiB
    __shared__ unsigned short lBs[NBUF][128 * 64]; // 3 x 16 KiB

    const int tid  = threadIdx.x;
    const int w    = tid >> 6;                 // wave 0..3
    const int lane = tid & 63;
    const int q    = lane >> 4;                // 0..3
    const int r    = lane & 15;                // 0..15

    const int mt   = w >> 1;                   // 16-row half (compute role)
    const int nh   = w & 1;                    // 64-col half
    const int row0 = blockIdx.x * 32;

    // ---- staging source indices (XOR swizzle applied on the GLOBAL side) ----
    // A: wave w stages rows [w*8, w*8+8), instr j in {0,1}:
    //    m = w*8 + j*4 + (lane>>4), g' = lane&15, source group g = g'^(m&15)
    int a_m[2], a_g[2];
#pragma unroll
    for (int j = 0; j < 2; ++j) {
        a_m[j] = w * 8 + j * 4 + (lane >> 4);
        a_g[j] = (lane & 15) ^ (a_m[j] & 15);
    }
    // B: wave w stages rows [w*32, w*32+32), instr j in {0..3}:
    //    n = w*32 + j*8 + (lane>>3), g' = lane&7, source group g = g'^(n&7)
    int b_n[4], b_g[4];
#pragma unroll
    for (int j = 0; j < 4; ++j) {
        b_n[j] = w * 32 + j * 8 + (lane >> 3);
        b_g[j] = (lane & 7) ^ (b_n[j] & 7);
    }

    // stage chunk kc into buffer buf (6 glds/wave, no VGPR round-trip)
    auto stage = [&](int kc, int buf) {
#pragma unroll
        for (int j = 0; j < 2; ++j)
            glds16(x + (size_t)(row0 + a_m[j]) * DD + kc * BK + a_g[j] * 4,
                   (char*)lAf[buf] + w * 2048 + j * 1024);
#pragma unroll
        for (int j = 0; j < 4; ++j)
            glds16(wt + (size_t)kc * 8192 + b_n[j] * 64 + b_g[j] * 8,
                   (char*)lBs[buf] + w * 4096 + j * 1024);
    };

    f32x4 acc[4];
#pragma unroll
    for (int nt = 0; nt < 4; ++nt) acc[nt] = (f32x4){0.f, 0.f, 0.f, 0.f};

    // ---- prologue: chunks 0 and 1 in flight
    stage(0, 0);
    stage(1, 1);

    for (int kc = 0; kc < NCHUNK; ++kc) {
        // wait for chunk kc only (6 newest = chunk kc+1 stay in flight), then
        // barrier WITHOUT full drain. Last iter: nothing younger -> vmcnt(0).
        if (kc < NCHUNK - 1) {
            asm volatile("s_waitcnt vmcnt(6)\n\ts_barrier" ::: "memory");
        } else {
            asm volatile("s_waitcnt vmcnt(0)\n\ts_barrier" ::: "memory");
        }

        // issue chunk kc+2 into buffer (kc+2)%3 (held kc-1: all readers passed
        // the barrier above -> WAR-safe)
        if (kc + 2 < NCHUNK) stage(kc + 2, (kc + 2) % NBUF);

        // ---- compute chunk kc
        const float* const lA = lAf[kc % NBUF];
        const unsigned short* const lB = lBs[kc % NBUF];
#pragma unroll
        for (int ks = 0; ks < 2; ++ks) {
            const int m  = mt * 16 + r;
            const int g0 = ks * 8 + q * 2;     // even global group
            const float4 lo = *(const float4*)(&lA[m * 64 + (((g0    ) ^ (m & 15)) * 4)]);
            const float4 hi = *(const float4*)(&lA[m * 64 + (((g0 + 1) ^ (m & 15)) * 4)]);
            union { unsigned short s[8]; short8 v; } pk;
            pk.s[0] = f2bf(lo.x); pk.s[1] = f2bf(lo.y);
            pk.s[2] = f2bf(lo.z); pk.s[3] = f2bf(lo.w);
            pk.s[4] = f2bf(hi.x); pk.s[5] = f2bf(hi.y);
            pk.s[6] = f2bf(hi.z); pk.s[7] = f2bf(hi.w);
            const short8 a = pk.v;

            short8 b[4];
            const int gb = ks * 4 + q;
#pragma unroll
            for (int nt = 0; nt < 4; ++nt) {
                const int n = nh * 64 + nt * 16 + r;
                b[nt] = *(const short8*)(&lB[n * 64 + ((gb ^ (n & 7)) * 8)]);
            }
#pragma unroll
            for (int nt = 0; nt < 4; ++nt)
                acc[nt] = __builtin_amdgcn_mfma_f32_16x16x32_bf16(a, b[nt], acc[nt], 0, 0, 0);
        }
        // no trailing barrier: next iteration's top barrier orders buffer reuse
    }

    // ---- epilogue: bias + boundary masks.  C/D: col=lane&15 (N), row=q*4+reg (M).
#pragma unroll
    for (int reg = 0; reg < 4; ++reg) {
        const int m = row0 + mt * 16 + q * 4 + reg;
        const int t = m & (TT - 1);
        const int cur  = mask[m];
        const int prev = (t != 0)      ? mask[m - 1] : 0;
        const int nxt  = (t != TT - 1) ? mask[m + 1] : 0;
        const float sm = (cur > prev) ? 1.f : 0.f;   // start_mask
        const float em = (nxt > cur)  ? 1.f : 0.f;   // end_mask
#pragma unroll
        for (int nt = 0; nt < 4; ++nt) {
            const int n = nh * 64 + nt * 16 + r;
            float e = acc[nt][reg] + bias[n] + sm * lb[n] + em * rb[n];
            out[(size_t)m * UU + n] = e;
        }
    }
}

extern "C" void kernel_launch(void* const* d_in, const int* in_sizes, int n_in,
                              void* d_out, int out_size, void* d_ws, size_t ws_size,
                              hipStream_t stream) {
    const float* x    = (const float*)d_in[0];
    const int*   mask = (const int*)d_in[1];
    const float* w    = (const float*)d_in[2];
    const float* bias = (const float*)d_in[3];
    const float* lb   = (const float*)d_in[4];
    const float* rb   = (const float*)d_in[5];
    float* out = (float*)d_out;
    unsigned short* wt = (unsigned short*)d_ws;   // 256 KiB bf16 Wt

    wprep_kernel<<<64, 256, 0, stream>>>(w, wt);
    // 1024 blocks, 72 KB LDS -> 2 blocks/CU; manual vmcnt pipeline inside
    crf_energy_kernel<<<1024, 256, 0, stream>>>(x, mask, wt, bias, lb, rb, out);
}